// Round 19
// baseline (368.736 us; speedup 1.0000x reference)
//
#include <hip/hip_runtime.h>
#include <hip/hip_bf16.h>

typedef float f4  __attribute__((ext_vector_type(4)));
typedef short s8v __attribute__((ext_vector_type(8)));
typedef short s4v __attribute__((ext_vector_type(4)));

#define MFMA16(a, b, c) __builtin_amdgcn_mfma_f32_16x16x32_bf16((a), (b), (c), 0, 0, 0)

// Packed RNE f32->bf16 pair via compiler intrinsic (emits v_cvt_pk_bf16_f32).
__device__ __forceinline__ unsigned cvtpk(float a, float b) {
  __hip_bfloat162 h2 = __float22bfloat162_rn(make_float2(a, b));
  unsigned u;
  __builtin_memcpy(&u, &h2, 4);
  return u;
}
__device__ __forceinline__ float bf2f(unsigned short s) {
  union { unsigned u; float f; } x; x.u = ((unsigned)s) << 16; return x.f;
}
__device__ __forceinline__ s8v cvt8(const float* p) {
  float4 a = *(const float4*)p;
  float4 b = *(const float4*)(p + 4);
  union { unsigned u[4]; s8v v; } r;
  r.u[0] = cvtpk(a.x, a.y); r.u[1] = cvtpk(a.z, a.w);
  r.u[2] = cvtpk(b.x, b.y); r.u[3] = cvtpk(b.z, b.w);
  return r.v;
}
__device__ __forceinline__ s8v mk8(unsigned a0, unsigned a1, unsigned b0, unsigned b1) {
  union { unsigned u[4]; s8v v; } r;
  r.u[0] = a0; r.u[1] = a1; r.u[2] = b0; r.u[3] = b1;
  return r.v;
}
// Two b64 LDS reads -> one 8-bf16 A-operand (slots j0..3 from p0, j4..7 from p1).
__device__ __forceinline__ s8v ld44(const short* p0, const short* p1) {
  s4v a = *(const s4v*)p0;
  s4v b = *(const s4v*)p1;
  s8v r;
  r[0] = a[0]; r[1] = a[1]; r[2] = a[2]; r[3] = a[3];
  r[4] = b[0]; r[5] = b[1]; r[6] = b[2]; r[7] = b[3];
  return r;
}

// R19: 512-thread blocks, ONE m-tile per wave (8 waves cover the 8 tiles).
// Rationale (R17/R18 post-mortem): waves are ~90% stalled on serial latency
// chains; resident-wave count is the lever. 512 threads -> 4 blocks/CU
// (thread-limited) x 8 waves = 32 waves/CU theoretical vs R17's 20, with
// LOWER per-wave pressure (one tile of state) and a shorter per-wave chain.
// Input is fp32 (R18 finding: in_npz=124MB) -> cvt8 path is the hot path.
// launch_bounds(512,4): empirical cap ~256/min_waves = 64 VGPR; designed
// pressure ~45-60. R18's spill (VGPR=64 + FETCH 141/WRITE 193MB) came from
// +32 prefetch regs; those are gone.
__global__ __launch_bounds__(512, 4)
void attn_head(const void* __restrict__ xg, const void* __restrict__ wqg,
               const void* __restrict__ wkg, const void* __restrict__ wvg,
               void* __restrict__ outg) {
  // LDS 32768 B. Ks: K[s][h] at s*64 + (h ^ ((s&15)<<2));
  // Vt: V^T[h][s] at h*128 + (s ^ ((h&15)<<2)). 8B granules, conflict-free
  // (R5/R6/R15/R17 measured SQ_LDS_BANK_CONFLICT = 0).
  __shared__ __align__(16) short smem[16384];
  short* Ksm = smem;           // 128*64 shorts
  short* Vt  = smem + 8192;    // 64*128 shorts

  const int tid  = threadIdx.x;
  const int m    = tid >> 6;         // wave = m-tile index 0..7
  const int lane = tid & 63;
  const int c16  = lane & 15;
  const int quad = lane >> 4;
  const int b    = blockIdx.x;
  const int swz  = c16 << 2;
  const int q4   = quad * 4;

  // ---- barrier-free dtype detect: every wave samples the SAME 64 shorts ----
  int isbf;
  {
    const unsigned short* w = (const unsigned short*)wqg;
    float f = bf2f(w[lane]);
    float a = fabsf(f);
    int ok = (f == 0.0f || (a >= 1e-4f && a <= 1e4f)) ? 1 : 0;
    unsigned long long ball = __ballot(ok);
    isbf = (__popcll(ball) >= 58) ? 1 : 0;
  }

  // ---- X fragments for this wave's tile ----
  s8v xf[2];
  {
    const size_t base = (size_t)b * 8192 + (size_t)(m * 16 + c16) * 64;
    #pragma unroll
    for (int kt = 0; kt < 2; kt++) {
      const int off = kt * 32 + quad * 8;
      if (isbf) xf[kt] = *(const s8v*)((const unsigned short*)xg + base + off);
      else      xf[kt] = cvt8((const float*)xg + base + off);
    }
  }

  // ---- phase 1: Q^T (packed bf16, 8 regs), K,V -> LDS (own tile only) ----
  unsigned qpk[4][2];
  #pragma unroll
  for (int ht = 0; ht < 4; ht++) {
    s8v wqf[2], wkf[2], wvf[2];
    const int woff0 = (ht * 16 + c16) * 64 + quad * 8;
    #pragma unroll
    for (int kt = 0; kt < 2; kt++) {
      const int off = woff0 + kt * 32;
      if (isbf) {
        wqf[kt] = *(const s8v*)((const unsigned short*)wqg + off);
        wkf[kt] = *(const s8v*)((const unsigned short*)wkg + off);
        wvf[kt] = *(const s8v*)((const unsigned short*)wvg + off);
      } else {
        wqf[kt] = cvt8((const float*)wqg + off);
        wkf[kt] = cvt8((const float*)wkg + off);
        wvf[kt] = cvt8((const float*)wvg + off);
      }
    }
    f4 z = {0.f, 0.f, 0.f, 0.f};
    f4 qt = z, kk = z, vv = z;
    qt = MFMA16(wqf[0], xf[0], qt);  qt = MFMA16(wqf[1], xf[1], qt);
    // swapped operands: lane holds h = ht*16+quad*4+r for s = m*16+c16
    kk = MFMA16(wkf[0], xf[0], kk);  kk = MFMA16(wkf[1], xf[1], kk);
    vv = MFMA16(xf[0], wvf[0], vv);  vv = MFMA16(xf[1], wvf[1], vv);
    qpk[ht][0] = cvtpk(qt[0] * 0.125f, qt[1] * 0.125f);
    qpk[ht][1] = cvtpk(qt[2] * 0.125f, qt[3] * 0.125f);
    {  // K[s][h]: one 8B swizzled store
      union { unsigned u[2]; s4v v; } pk;
      pk.u[0] = cvtpk(kk[0], kk[1]); pk.u[1] = cvtpk(kk[2], kk[3]);
      *(s4v*)(Ksm + (m * 16 + c16) * 64 + ((ht * 16 + q4) ^ swz)) = pk.v;
    }
    {  // V^T[h][s]: one 8B swizzled store
      union { unsigned u[2]; s4v v; } pv;
      pv.u[0] = cvtpk(vv[0], vv[1]); pv.u[1] = cvtpk(vv[2], vv[3]);
      *(s4v*)(Vt + (ht * 16 + c16) * 128 + ((m * 16 + q4) ^ swz)) = pv.v;
    }
  }

  __syncthreads();   // only barrier

  // ---- phase 2: fused per-kt S^T -> exp -> P^T -> PV for tile m ----
  const s8v qb0 = mk8(qpk[0][0], qpk[0][1], qpk[1][0], qpk[1][1]);
  const s8v qb1 = mk8(qpk[2][0], qpk[2][1], qpk[3][0], qpk[3][1]);

  f4 acc[4];
  #pragma unroll
  for (int ht = 0; ht < 4; ht++) { f4 z = {0.f,0.f,0.f,0.f}; acc[ht] = z; }
  float sum = 0.f;
  const int nchunk = (m >> 1) + 1;

  #pragma unroll
  for (int kt = 0; kt < 4; kt++) {
    if (kt >= nchunk) continue;           // wave-uniform causal K-range
    const int nt0 = 2 * kt, nt1 = 2 * kt + 1;
    const bool hb = nt1 <= m;             // wave-uniform

    f4 z = {0.f, 0.f, 0.f, 0.f};
    f4 s0 = z, s1 = z;
    {
      const short* kr = Ksm + (nt0 * 16 + c16) * 64;
      s0 = MFMA16(ld44(kr + ((q4     ) ^ swz), kr + ((q4 + 16) ^ swz)), qb0, s0);
      s0 = MFMA16(ld44(kr + ((q4 + 32) ^ swz), kr + ((q4 + 48) ^ swz)), qb1, s0);
    }
    if (hb) {
      const short* kr = Ksm + (nt1 * 16 + c16) * 64;
      s1 = MFMA16(ld44(kr + ((q4     ) ^ swz), kr + ((q4 + 16) ^ swz)), qb0, s1);
      s1 = MFMA16(ld44(kr + ((q4 + 32) ^ swz), kr + ((q4 + 48) ^ swz)), qb1, s1);
    }
    #pragma unroll
    for (int r = 0; r < 4; r++) {
      const bool k0 = (nt0 < m) || (q4 + r <= c16);
      float e0 = k0 ? __expf(s0[r]) : 0.0f;
      s0[r] = e0; sum += e0;
    }
    if (hb) {
      #pragma unroll
      for (int r = 0; r < 4; r++) {
        const bool k1 = (nt1 < m) || (q4 + r <= c16);
        float e1 = k1 ? __expf(s1[r]) : 0.0f;
        s1[r] = e1; sum += e1;
      }
    }
    // s1 stays all-zero when !hb -> upper half of pb packs to 0 (correct).
    const s8v pb = mk8(cvtpk(s0[0], s0[1]), cvtpk(s0[2], s0[3]),
                       cvtpk(s1[0], s1[1]), cvtpk(s1[2], s1[3]));
    #pragma unroll
    for (int ht = 0; ht < 4; ht++) {
      const short* vr = Vt + (ht * 16 + c16) * 128;
      const s8v va = ld44(vr + ((kt * 32 + q4     ) ^ swz),
                          vr + ((kt * 32 + q4 + 16) ^ swz));
      acc[ht] = MFMA16(va, pb, acc[ht]);
    }
  }

  sum += __shfl_xor(sum, 16);
  sum += __shfl_xor(sum, 32);
  const float inv = 1.0f / sum;           // normalize in epilogue

  // epilogue: O^T lane holds 4 consecutive h for query t=c16 -> 8/16B stores
  if (isbf) {
    unsigned short* op = (unsigned short*)outg + (size_t)b * 8192;
    #pragma unroll
    for (int ht = 0; ht < 4; ht++) {
      union { unsigned u[2]; s4v v; } o;
      o.u[0] = cvtpk(acc[ht][0] * inv, acc[ht][1] * inv);
      o.u[1] = cvtpk(acc[ht][2] * inv, acc[ht][3] * inv);
      *(s4v*)(op + (size_t)(m * 16 + c16) * 64 + ht * 16 + q4) = o.v;
    }
  } else {
    float* op = (float*)outg + (size_t)b * 8192;
    #pragma unroll
    for (int ht = 0; ht < 4; ht++) {
      float4 o = {acc[ht][0] * inv, acc[ht][1] * inv,
                  acc[ht][2] * inv, acc[ht][3] * inv};
      *(float4*)(op + (size_t)(m * 16 + c16) * 64 + ht * 16 + q4) = o;
    }
  }
}

extern "C" void kernel_launch(void* const* d_in, const int* in_sizes, int n_in,
                              void* d_out, int out_size, void* d_ws, size_t ws_size,
                              hipStream_t stream) {
  (void)d_ws; (void)ws_size; (void)in_sizes; (void)n_in; (void)out_size;
  attn_head<<<dim3(4096), dim3(512), 0, stream>>>(
      d_in[0], d_in[1], d_in[2], d_in[3], d_out);
}

// Round 20
// 274.367 us; speedup vs baseline: 1.3440x; 1.3440x over previous
//
#include <hip/hip_runtime.h>
#include <hip/hip_bf16.h>

typedef float f4  __attribute__((ext_vector_type(4)));
typedef short s8v __attribute__((ext_vector_type(8)));
typedef short s4v __attribute__((ext_vector_type(4)));

#define MFMA16(a, b, c) __builtin_amdgcn_mfma_f32_16x16x32_bf16((a), (b), (c), 0, 0, 0)

// Packed RNE f32->bf16 pair via compiler intrinsic (emits v_cvt_pk_bf16_f32).
__device__ __forceinline__ unsigned cvtpk(float a, float b) {
  __hip_bfloat162 h2 = __float22bfloat162_rn(make_float2(a, b));
  unsigned u;
  __builtin_memcpy(&u, &h2, 4);
  return u;
}
__device__ __forceinline__ float bf2f(unsigned short s) {
  union { unsigned u; float f; } x; x.u = ((unsigned)s) << 16; return x.f;
}
__device__ __forceinline__ s8v cvt8(const float* p) {
  float4 a = *(const float4*)p;
  float4 b = *(const float4*)(p + 4);
  union { unsigned u[4]; s8v v; } r;
  r.u[0] = cvtpk(a.x, a.y); r.u[1] = cvtpk(a.z, a.w);
  r.u[2] = cvtpk(b.x, b.y); r.u[3] = cvtpk(b.z, b.w);
  return r.v;
}
__device__ __forceinline__ s8v mk8(unsigned a0, unsigned a1, unsigned b0, unsigned b1) {
  union { unsigned u[4]; s8v v; } r;
  r.u[0] = a0; r.u[1] = a1; r.u[2] = b0; r.u[3] = b1;
  return r.v;
}
// Two b64 LDS reads -> one 8-bf16 A-operand (slots j0..3 from p0, j4..7 from p1).
__device__ __forceinline__ s8v ld44(const short* p0, const short* p1) {
  s4v a = *(const s4v*)p0;
  s4v b = *(const s4v*)p1;
  s8v r;
  r[0] = a[0]; r[1] = a[1]; r[2] = a[2]; r[3] = a[3];
  r[4] = b[0]; r[5] = b[1]; r[6] = b[2]; r[7] = b[3];
  return r;
}

// Pre-pass: detect weight dtype, write Wq|Wk|Wv as bf16 into workspace.
// R17<->R19 controlled comparison: doubling per-CU weight-load work cost
// +70us -> ~half of R17's 145us is redundant per-wave W load+convert.
// This does the conversion ONCE (12288 elems) instead of per-wave.
__global__ void conv_w(const void* __restrict__ wq, const void* __restrict__ wk,
                       const void* __restrict__ wv, unsigned short* __restrict__ wsp) {
  const int tid = threadIdx.x;
  int isbf;
  {
    const unsigned short* w = (const unsigned short*)wq;
    float f = bf2f(w[tid & 63]);
    float a = fabsf(f);
    int ok = (f == 0.0f || (a >= 1e-4f && a <= 1e4f)) ? 1 : 0;
    unsigned long long ball = __ballot(ok);
    isbf = (__popcll(ball) >= 58) ? 1 : 0;
  }
  const void* srcs[3] = {wq, wk, wv};
  #pragma unroll
  for (int wi = 0; wi < 3; wi++) {
    s4v* dst = (s4v*)(wsp + wi * 4096);
    if (isbf) {
      const s4v* s = (const s4v*)srcs[wi];
      for (int i = tid; i < 1024; i += 256) dst[i] = s[i];
    } else {
      const float4* s = (const float4*)srcs[wi];
      for (int i = tid; i < 1024; i += 256) {
        float4 v = s[i];
        union { unsigned u[2]; s4v v4; } p;
        p.u[0] = cvtpk(v.x, v.y); p.u[1] = cvtpk(v.z, v.w);
        dst[i] = p.v4;
      }
    }
  }
}

// R20 = R17 structure (best measured: 145us, VGPR 52, no spill) + bf16
// weights from workspace (wmode=1) -> no per-wave weight cvtpk, half the
// weight L2 bytes. wmode=0 falls back to in-kernel conversion (ws too small).
__global__ __launch_bounds__(256, 4)
void attn_head(const void* __restrict__ xg, const void* __restrict__ wdet,
               const void* __restrict__ wqp, const void* __restrict__ wkp,
               const void* __restrict__ wvp, void* __restrict__ outg, int wmode) {
  // LDS 32768 B -> 5 blocks/CU LDS-wise.
  // Ks: K[s][h] at s*64 + (h ^ ((s&15)<<2));  Vt: V^T[h][s] at h*128 + (s ^ ...)
  // 8B granules, conflict-free (R5/R6/R15/R17 measured 0 conflicts).
  __shared__ __align__(16) short smem[16384];
  short* Ksm = smem;           // 128*64 shorts
  short* Vt  = smem + 8192;    // 64*128 shorts

  const int tid  = threadIdx.x;
  const int wave = tid >> 6;
  const int lane = tid & 63;
  const int c16  = lane & 15;
  const int quad = lane >> 4;
  const int b    = blockIdx.x;
  const int swz  = c16 << 2;

  // ---- barrier-free dtype detect (X/epilogue path) on ORIGINAL weights ----
  int isbf;
  {
    const unsigned short* w = (const unsigned short*)wdet;
    float f = bf2f(w[lane]);
    float a = fabsf(f);
    int ok = (f == 0.0f || (a >= 1e-4f && a <= 1e4f)) ? 1 : 0;
    unsigned long long ball = __ballot(ok);
    isbf = (__popcll(ball) >= 58) ? 1 : 0;
  }
  const int wbf = wmode | isbf;   // weights bf16? (forced when pre-converted)

  const int mts[2] = {wave, 7 - wave};   // balanced causal split

  // ---- X fragments ----
  s8v xf[2][2];
  #pragma unroll
  for (int mi = 0; mi < 2; mi++) {
    const size_t base = (size_t)b * 8192 + (size_t)(mts[mi] * 16 + c16) * 64;
    #pragma unroll
    for (int kt = 0; kt < 2; kt++) {
      const int off = kt * 32 + quad * 8;
      if (isbf) xf[mi][kt] = *(const s8v*)((const unsigned short*)xg + base + off);
      else      xf[mi][kt] = cvt8((const float*)xg + base + off);
    }
  }

  // ---- phase 1: Q^T (packed bf16, 16 regs), K,V -> LDS ----
  unsigned qpk[2][4][2];   // [mi][ht][pair]
  #pragma unroll
  for (int ht = 0; ht < 4; ht++) {
    s8v wqf[2], wkf[2], wvf[2];
    const int woff0 = (ht * 16 + c16) * 64 + quad * 8;
    #pragma unroll
    for (int kt = 0; kt < 2; kt++) {
      const int off = woff0 + kt * 32;
      if (wbf) {
        wqf[kt] = *(const s8v*)((const unsigned short*)wqp + off);
        wkf[kt] = *(const s8v*)((const unsigned short*)wkp + off);
        wvf[kt] = *(const s8v*)((const unsigned short*)wvp + off);
      } else {
        wqf[kt] = cvt8((const float*)wqp + off);
        wkf[kt] = cvt8((const float*)wkp + off);
        wvf[kt] = cvt8((const float*)wvp + off);
      }
    }
    #pragma unroll
    for (int mi = 0; mi < 2; mi++) {
      const int m = mts[mi];
      f4 z = {0.f, 0.f, 0.f, 0.f};
      f4 qt = z, kk = z, vv = z;
      qt = MFMA16(wqf[0], xf[mi][0], qt);  qt = MFMA16(wqf[1], xf[mi][1], qt);
      // swapped operands: lane holds h = ht*16+quad*4+r for s = m*16+c16
      kk = MFMA16(wkf[0], xf[mi][0], kk);  kk = MFMA16(wkf[1], xf[mi][1], kk);
      vv = MFMA16(xf[mi][0], wvf[0], vv);  vv = MFMA16(xf[mi][1], wvf[1], vv);
      qpk[mi][ht][0] = cvtpk(qt[0] * 0.125f, qt[1] * 0.125f);
      qpk[mi][ht][1] = cvtpk(qt[2] * 0.125f, qt[3] * 0.125f);
      {  // K[s][h]: one 8B swizzled store
        union { unsigned u[2]; s4v v; } pk;
        pk.u[0] = cvtpk(kk[0], kk[1]); pk.u[1] = cvtpk(kk[2], kk[3]);
        *(s4v*)(Ksm + (m * 16 + c16) * 64 + ((ht * 16 + quad * 4) ^ swz)) = pk.v;
      }
      {  // V^T[h][s]: one 8B swizzled store
        union { unsigned u[2]; s4v v; } pv;
        pv.u[0] = cvtpk(vv[0], vv[1]); pv.u[1] = cvtpk(vv[2], vv[3]);
        *(s4v*)(Vt + (ht * 16 + c16) * 128 + ((m * 16 + quad * 4) ^ swz)) = pv.v;
      }
    }
  }

  __syncthreads();   // only barrier

  // ---- phase 2 per M-tile: fused per-kt S^T -> exp -> P^T -> PV ----
  #pragma unroll
  for (int mi = 0; mi < 2; mi++) {
    const int m = mts[mi];
    const int q4 = quad * 4;
    const s8v qb0 = mk8(qpk[mi][0][0], qpk[mi][0][1], qpk[mi][1][0], qpk[mi][1][1]);
    const s8v qb1 = mk8(qpk[mi][2][0], qpk[mi][2][1], qpk[mi][3][0], qpk[mi][3][1]);

    f4 acc[4];
    #pragma unroll
    for (int ht = 0; ht < 4; ht++) { f4 z = {0.f,0.f,0.f,0.f}; acc[ht] = z; }
    float sum = 0.f;
    const int nchunk = (m >> 1) + 1;

    #pragma unroll
    for (int kt = 0; kt < 4; kt++) {
      if (kt >= nchunk) continue;           // wave-uniform causal K-range
      const int nt0 = 2 * kt, nt1 = 2 * kt + 1;
      const bool hb = nt1 <= m;             // wave-uniform

      f4 z = {0.f, 0.f, 0.f, 0.f};
      f4 s0 = z, s1 = z;
      {
        const short* kr = Ksm + (nt0 * 16 + c16) * 64;
        s0 = MFMA16(ld44(kr + ((q4     ) ^ swz), kr + ((q4 + 16) ^ swz)), qb0, s0);
        s0 = MFMA16(ld44(kr + ((q4 + 32) ^ swz), kr + ((q4 + 48) ^ swz)), qb1, s0);
      }
      if (hb) {
        const short* kr = Ksm + (nt1 * 16 + c16) * 64;
        s1 = MFMA16(ld44(kr + ((q4     ) ^ swz), kr + ((q4 + 16) ^ swz)), qb0, s1);
        s1 = MFMA16(ld44(kr + ((q4 + 32) ^ swz), kr + ((q4 + 48) ^ swz)), qb1, s1);
      }
      #pragma unroll
      for (int r = 0; r < 4; r++) {
        const bool k0 = (nt0 < m) || (q4 + r <= c16);
        float e0 = k0 ? __expf(s0[r]) : 0.0f;
        s0[r] = e0; sum += e0;
      }
      if (hb) {
        #pragma unroll
        for (int r = 0; r < 4; r++) {
          const bool k1 = (nt1 < m) || (q4 + r <= c16);
          float e1 = k1 ? __expf(s1[r]) : 0.0f;
          s1[r] = e1; sum += e1;
        }
      }
      // s1 stays all-zero when !hb -> upper half of pb packs to 0 (correct).
      const s8v pb = mk8(cvtpk(s0[0], s0[1]), cvtpk(s0[2], s0[3]),
                         cvtpk(s1[0], s1[1]), cvtpk(s1[2], s1[3]));
      #pragma unroll
      for (int ht = 0; ht < 4; ht++) {
        const short* vr = Vt + (ht * 16 + c16) * 128;
        const s8v va = ld44(vr + ((kt * 32 + q4     ) ^ swz),
                            vr + ((kt * 32 + q4 + 16) ^ swz));
        acc[ht] = MFMA16(va, pb, acc[ht]);
      }
    }

    sum += __shfl_xor(sum, 16);
    sum += __shfl_xor(sum, 32);
    const float inv = 1.0f / sum;           // normalize in epilogue

    // epilogue: O^T lane holds 4 consecutive h for query t=c16
    if (isbf) {
      unsigned short* op = (unsigned short*)outg + (size_t)b * 8192;
      #pragma unroll
      for (int ht = 0; ht < 4; ht++) {
        union { unsigned u[2]; s4v v; } o;
        o.u[0] = cvtpk(acc[ht][0] * inv, acc[ht][1] * inv);
        o.u[1] = cvtpk(acc[ht][2] * inv, acc[ht][3] * inv);
        *(s4v*)(op + (size_t)(m * 16 + c16) * 64 + ht * 16 + quad * 4) = o.v;
      }
    } else {
      float* op = (float*)outg + (size_t)b * 8192;
      #pragma unroll
      for (int ht = 0; ht < 4; ht++) {
        float4 o = {acc[ht][0] * inv, acc[ht][1] * inv,
                    acc[ht][2] * inv, acc[ht][3] * inv};
        *(float4*)(op + (size_t)(m * 16 + c16) * 64 + ht * 16 + quad * 4) = o;
      }
    }
  }
}

extern "C" void kernel_launch(void* const* d_in, const int* in_sizes, int n_in,
                              void* d_out, int out_size, void* d_ws, size_t ws_size,
                              hipStream_t stream) {
  (void)in_sizes; (void)n_in; (void)out_size;
  if (ws_size >= 3 * 4096 * sizeof(unsigned short)) {
    unsigned short* wsp = (unsigned short*)d_ws;
    conv_w<<<dim3(1), dim3(256), 0, stream>>>(d_in[1], d_in[2], d_in[3], wsp);
    attn_head<<<dim3(4096), dim3(256), 0, stream>>>(
        d_in[0], d_in[1], wsp, wsp + 4096, wsp + 8192, d_out, 1);
  } else {
    attn_head<<<dim3(4096), dim3(256), 0, stream>>>(
        d_in[0], d_in[1], d_in[1], d_in[2], d_in[3], d_out, 0);
  }
}

// Round 21
// 273.109 us; speedup vs baseline: 1.3501x; 1.0046x over previous
//
#include <hip/hip_runtime.h>
#include <hip/hip_bf16.h>

typedef float f4  __attribute__((ext_vector_type(4)));
typedef short s8v __attribute__((ext_vector_type(8)));
typedef short s4v __attribute__((ext_vector_type(4)));

#define MFMA16(a, b, c) __builtin_amdgcn_mfma_f32_16x16x32_bf16((a), (b), (c), 0, 0, 0)

// Packed RNE f32->bf16 pair via compiler intrinsic (emits v_cvt_pk_bf16_f32).
__device__ __forceinline__ unsigned cvtpk(float a, float b) {
  __hip_bfloat162 h2 = __float22bfloat162_rn(make_float2(a, b));
  unsigned u;
  __builtin_memcpy(&u, &h2, 4);
  return u;
}
__device__ __forceinline__ s8v cvt8(const float* p) {
  float4 a = *(const float4*)p;
  float4 b = *(const float4*)(p + 4);
  union { unsigned u[4]; s8v v; } r;
  r.u[0] = cvtpk(a.x, a.y); r.u[1] = cvtpk(a.z, a.w);
  r.u[2] = cvtpk(b.x, b.y); r.u[3] = cvtpk(b.z, b.w);
  return r.v;
}
__device__ __forceinline__ s8v mk8(unsigned a0, unsigned a1, unsigned b0, unsigned b1) {
  union { unsigned u[4]; s8v v; } r;
  r.u[0] = a0; r.u[1] = a1; r.u[2] = b0; r.u[3] = b1;
  return r.v;
}
// Two b64 LDS reads -> one 8-bf16 A-operand (slots j0..3 from p0, j4..7 from p1).
__device__ __forceinline__ s8v ld44(const short* p0, const short* p1) {
  s4v a = *(const s4v*)p0;
  s4v b = *(const s4v*)p1;
  s8v r;
  r[0] = a[0]; r[1] = a[1]; r[2] = a[2]; r[3] = a[3];
  r[4] = b[0]; r[5] = b[1]; r[6] = b[2]; r[7] = b[3];
  return r;
}

// Pre-pass (only launched when weights are fp32): write Wq|Wk|Wv as bf16
// into workspace. R17<->R19 controlled comparison: per-wave W load+convert
// was ~half of R17's time; conversion now happens ONCE (R20: 145->111us).
__global__ void conv_w(const void* __restrict__ wq, const void* __restrict__ wk,
                       const void* __restrict__ wv, unsigned short* __restrict__ wsp) {
  const int tid = threadIdx.x;
  const void* srcs[3] = {wq, wk, wv};
  #pragma unroll
  for (int wi = 0; wi < 3; wi++) {
    s4v* dst = (s4v*)(wsp + wi * 4096);
    const float4* s = (const float4*)srcs[wi];
    for (int i = tid; i < 1024; i += 256) {
      float4 v = s[i];
      union { unsigned u[2]; s4v v4; } p;
      p.u[0] = cvtpk(v.x, v.y); p.u[1] = cvtpk(v.z, v.w);
      dst[i] = p.v4;
    }
  }
}

// R21 = R20 structure (best: 111.6us, VGPR 52, no spill) with dtype resolved
// HOST-side from in_sizes (x elems*4 vs *2) -> no ballot detect; X loads
// issue at wave start with no serialization behind a uniform global load.
// Row-sum split into 2 accumulators (halves the 72-add serial VALU chain).
__global__ __launch_bounds__(256, 4)
void attn_head(const void* __restrict__ xg, const void* __restrict__ wqp,
               const void* __restrict__ wkp, const void* __restrict__ wvp,
               void* __restrict__ outg, int xbf, int wbf) {
  // LDS 32768 B -> 5 blocks/CU LDS-wise.
  // Ks: K[s][h] at s*64 + (h ^ ((s&15)<<2));  Vt: V^T[h][s] at h*128 + (s ^ ...)
  // 8B granules, conflict-free (R5/R6/R15/R17/R20 measured 0 conflicts).
  __shared__ __align__(16) short smem[16384];
  short* Ksm = smem;           // 128*64 shorts
  short* Vt  = smem + 8192;    // 64*128 shorts

  const int tid  = threadIdx.x;
  const int wave = tid >> 6;
  const int lane = tid & 63;
  const int c16  = lane & 15;
  const int quad = lane >> 4;
  const int b    = blockIdx.x;
  const int swz  = c16 << 2;

  const int mts[2] = {wave, 7 - wave};   // balanced causal split

  // ---- X fragments (issue immediately; dtype known from kernel arg) ----
  s8v xf[2][2];
  #pragma unroll
  for (int mi = 0; mi < 2; mi++) {
    const size_t base = (size_t)b * 8192 + (size_t)(mts[mi] * 16 + c16) * 64;
    #pragma unroll
    for (int kt = 0; kt < 2; kt++) {
      const int off = kt * 32 + quad * 8;
      if (xbf) xf[mi][kt] = *(const s8v*)((const unsigned short*)xg + base + off);
      else     xf[mi][kt] = cvt8((const float*)xg + base + off);
    }
  }

  // ---- phase 1: Q^T (packed bf16, 16 regs), K,V -> LDS ----
  unsigned qpk[2][4][2];   // [mi][ht][pair]
  #pragma unroll
  for (int ht = 0; ht < 4; ht++) {
    s8v wqf[2], wkf[2], wvf[2];
    const int woff0 = (ht * 16 + c16) * 64 + quad * 8;
    #pragma unroll
    for (int kt = 0; kt < 2; kt++) {
      const int off = woff0 + kt * 32;
      if (wbf) {
        wqf[kt] = *(const s8v*)((const unsigned short*)wqp + off);
        wkf[kt] = *(const s8v*)((const unsigned short*)wkp + off);
        wvf[kt] = *(const s8v*)((const unsigned short*)wvp + off);
      } else {
        wqf[kt] = cvt8((const float*)wqp + off);
        wkf[kt] = cvt8((const float*)wkp + off);
        wvf[kt] = cvt8((const float*)wvp + off);
      }
    }
    #pragma unroll
    for (int mi = 0; mi < 2; mi++) {
      const int m = mts[mi];
      f4 z = {0.f, 0.f, 0.f, 0.f};
      f4 qt = z, kk = z, vv = z;
      qt = MFMA16(wqf[0], xf[mi][0], qt);  qt = MFMA16(wqf[1], xf[mi][1], qt);
      // swapped operands: lane holds h = ht*16+quad*4+r for s = m*16+c16
      kk = MFMA16(wkf[0], xf[mi][0], kk);  kk = MFMA16(wkf[1], xf[mi][1], kk);
      vv = MFMA16(xf[mi][0], wvf[0], vv);  vv = MFMA16(xf[mi][1], wvf[1], vv);
      qpk[mi][ht][0] = cvtpk(qt[0] * 0.125f, qt[1] * 0.125f);
      qpk[mi][ht][1] = cvtpk(qt[2] * 0.125f, qt[3] * 0.125f);
      {  // K[s][h]: one 8B swizzled store
        union { unsigned u[2]; s4v v; } pk;
        pk.u[0] = cvtpk(kk[0], kk[1]); pk.u[1] = cvtpk(kk[2], kk[3]);
        *(s4v*)(Ksm + (m * 16 + c16) * 64 + ((ht * 16 + quad * 4) ^ swz)) = pk.v;
      }
      {  // V^T[h][s]: one 8B swizzled store
        union { unsigned u[2]; s4v v; } pv;
        pv.u[0] = cvtpk(vv[0], vv[1]); pv.u[1] = cvtpk(vv[2], vv[3]);
        *(s4v*)(Vt + (ht * 16 + c16) * 128 + ((m * 16 + quad * 4) ^ swz)) = pv.v;
      }
    }
  }

  __syncthreads();   // only barrier

  // ---- phase 2 per M-tile: fused per-kt S^T -> exp -> P^T -> PV ----
  #pragma unroll
  for (int mi = 0; mi < 2; mi++) {
    const int m = mts[mi];
    const int q4 = quad * 4;
    const s8v qb0 = mk8(qpk[mi][0][0], qpk[mi][0][1], qpk[mi][1][0], qpk[mi][1][1]);
    const s8v qb1 = mk8(qpk[mi][2][0], qpk[mi][2][1], qpk[mi][3][0], qpk[mi][3][1]);

    f4 acc[4];
    #pragma unroll
    for (int ht = 0; ht < 4; ht++) { f4 z = {0.f,0.f,0.f,0.f}; acc[ht] = z; }
    float sumA = 0.f, sumB = 0.f;    // split accumulators: halve the serial chain
    const int nchunk = (m >> 1) + 1;

    #pragma unroll
    for (int kt = 0; kt < 4; kt++) {
      if (kt >= nchunk) continue;           // wave-uniform causal K-range
      const int nt0 = 2 * kt, nt1 = 2 * kt + 1;
      const bool hb = nt1 <= m;             // wave-uniform

      f4 z = {0.f, 0.f, 0.f, 0.f};
      f4 s0 = z, s1 = z;
      {
        const short* kr = Ksm + (nt0 * 16 + c16) * 64;
        s0 = MFMA16(ld44(kr + ((q4     ) ^ swz), kr + ((q4 + 16) ^ swz)), qb0, s0);
        s0 = MFMA16(ld44(kr + ((q4 + 32) ^ swz), kr + ((q4 + 48) ^ swz)), qb1, s0);
      }
      if (hb) {
        const short* kr = Ksm + (nt1 * 16 + c16) * 64;
        s1 = MFMA16(ld44(kr + ((q4     ) ^ swz), kr + ((q4 + 16) ^ swz)), qb0, s1);
        s1 = MFMA16(ld44(kr + ((q4 + 32) ^ swz), kr + ((q4 + 48) ^ swz)), qb1, s1);
      }
      #pragma unroll
      for (int r = 0; r < 4; r++) {
        const bool k0 = (nt0 < m) || (q4 + r <= c16);
        float e0 = k0 ? __expf(s0[r]) : 0.0f;
        s0[r] = e0; sumA += e0;
      }
      if (hb) {
        #pragma unroll
        for (int r = 0; r < 4; r++) {
          const bool k1 = (nt1 < m) || (q4 + r <= c16);
          float e1 = k1 ? __expf(s1[r]) : 0.0f;
          s1[r] = e1; sumB += e1;
        }
      }
      // s1 stays all-zero when !hb -> upper half of pb packs to 0 (correct).
      const s8v pb = mk8(cvtpk(s0[0], s0[1]), cvtpk(s0[2], s0[3]),
                         cvtpk(s1[0], s1[1]), cvtpk(s1[2], s1[3]));
      #pragma unroll
      for (int ht = 0; ht < 4; ht++) {
        const short* vr = Vt + (ht * 16 + c16) * 128;
        const s8v va = ld44(vr + ((kt * 32 + q4     ) ^ swz),
                            vr + ((kt * 32 + q4 + 16) ^ swz));
        acc[ht] = MFMA16(va, pb, acc[ht]);
      }
    }

    float sum = sumA + sumB;
    sum += __shfl_xor(sum, 16);
    sum += __shfl_xor(sum, 32);
    const float inv = 1.0f / sum;           // normalize in epilogue

    // epilogue: O^T lane holds 4 consecutive h for query t=c16
    if (xbf) {
      unsigned short* op = (unsigned short*)outg + (size_t)b * 8192;
      #pragma unroll
      for (int ht = 0; ht < 4; ht++) {
        union { unsigned u[2]; s4v v; } o;
        o.u[0] = cvtpk(acc[ht][0] * inv, acc[ht][1] * inv);
        o.u[1] = cvtpk(acc[ht][2] * inv, acc[ht][3] * inv);
        *(s4v*)(op + (size_t)(m * 16 + c16) * 64 + ht * 16 + quad * 4) = o.v;
      }
    } else {
      float* op = (float*)outg + (size_t)b * 8192;
      #pragma unroll
      for (int ht = 0; ht < 4; ht++) {
        float4 o = {acc[ht][0] * inv, acc[ht][1] * inv,
                    acc[ht][2] * inv, acc[ht][3] * inv};
        *(float4*)(op + (size_t)(m * 16 + c16) * 64 + ht * 16 + quad * 4) = o;
      }
    }
  }
}

extern "C" void kernel_launch(void* const* d_in, const int* in_sizes, int n_in,
                              void* d_out, int out_size, void* d_ws, size_t ws_size,
                              hipStream_t stream) {
  (void)out_size;
  // Host-side dtype inference from buffer sizes (x: 4096*128*64 elems;
  // W: 64*64 elems). fp32 -> elems*4 bytes, bf16 -> elems*2.
  const int xbytes_bf16 = 4096 * 128 * 64 * 2;   // 67108864, fits int
  const int wbytes_bf16 = 64 * 64 * 2;           // 8192
  const int xbf = (n_in > 0 && in_sizes[0] == xbytes_bf16) ? 1 : 0;
  const int wbf = (n_in > 1 && in_sizes[1] == wbytes_bf16) ? 1 : 0;

  if (!wbf && ws_size >= 3 * 4096 * sizeof(unsigned short)) {
    // fp32 weights: convert once to bf16 in workspace.
    unsigned short* wsp = (unsigned short*)d_ws;
    conv_w<<<dim3(1), dim3(256), 0, stream>>>(d_in[1], d_in[2], d_in[3], wsp);
    attn_head<<<dim3(4096), dim3(256), 0, stream>>>(
        d_in[0], wsp, wsp + 4096, wsp + 8192, d_out, xbf, 1);
  } else {
    // bf16 weights (use originals) or no workspace (in-kernel convert).
    attn_head<<<dim3(4096), dim3(256), 0, stream>>>(
        d_in[0], d_in[1], d_in[2], d_in[3], d_out, xbf, wbf);
  }
}